// Round 16
// baseline (402.814 us; speedup 1.0000x reference)
//
#include <hip/hip_runtime.h>
#include <math.h>

#define BATCH   65536
#define DIM     64
#define HID     128
#define SPLIT   32
#define NBINS   8
#define PDIM    25          // 3*NBINS+1
#define NLAYERS 6
#define R_MIN   (-5.0f)
#define R_MAX   (5.0f)
#define MIN_BIN   1.0e-4f
#define MIN_SLOPE 1.0e-4f
#define SOFF      0.54116666f   // log(exp(1-MIN_SLOPE)-1)

#define ROWSW 16      // rows per wave
#define WAVES 4
#define MBLK  64      // rows per block
#define NT    256

#define N_W1  (HID*SPLIT)      // 4096
#define N_W2  (HID*HID)        // 16384
#define N_W4P (32*32*HID)      // 131072 (8 tb x 8 pq x 4 kt chunks of 512)
#define N_W4  (SPLIT*PDIM*HID) // 102400

typedef __attribute__((ext_vector_type(8))) short bf16x8;
typedef __attribute__((ext_vector_type(4))) float f32x4;

__device__ __forceinline__ short f2bf(float f) {
    unsigned u = __builtin_bit_cast(unsigned, f);
    unsigned r = u + 0x7FFFu + ((u >> 16) & 1u);   // RNE
    return (short)(r >> 16);
}

__device__ __forceinline__ unsigned pk2(float a, float b) {   // 2xf32 -> packed bf16 (RNE)
    unsigned r;
    asm("v_cvt_pk_bf16_f32 %0, %1, %2" : "=v"(r) : "v"(a), "v"(b));
    return r;
}

// act LDS layout: [group g = k>>2][row r][k&3] shorts, group stride 64 shorts.
__device__ __forceinline__ bf16x8 ldfrag(const short* base) {
    short4 lo = *reinterpret_cast<const short4*>(base);
    short4 hi = *reinterpret_cast<const short4*>(base + 64);
    bf16x8 a;
    a[0]=lo.x; a[1]=lo.y; a[2]=lo.z; a[3]=lo.w;
    a[4]=hi.x; a[5]=hi.y; a[6]=hi.z; a[7]=hi.w;
    return a;
}

// ---- weight conversion prologue (fragment packing, same as R5-R15) ----
__global__ void cvt_weights(const float* __restrict__ W1, const float* __restrict__ W2,
                            const float* __restrict__ W3, const float* __restrict__ W4,
                            const float* __restrict__ b4,
                            short* __restrict__ o1, short* __restrict__ o2,
                            short* __restrict__ o3, short* __restrict__ o4,
                            float* __restrict__ b4q) {
    const int stride = gridDim.x * blockDim.x;
    const int i0 = blockIdx.x * blockDim.x + threadIdx.x;
    for (int i = i0; i < NLAYERS*N_W1; i += stride) {
        const int L = i >> 12, rem = i & 4095;
        const int nt = rem >> 9, q = rem & 511;
        const int l = q >> 3, e = q & 7;
        o1[i] = f2bf(W1[L*N_W1 + (nt*16 + (l&15))*SPLIT + (l>>4)*8 + e]);
    }
    for (int i = i0; i < NLAYERS*N_W2; i += stride) {
        const int L = i >> 14, rem = i & 16383;
        const int c = rem >> 9, q = rem & 511;
        const int nt = c >> 2, kt = c & 3;
        const int l = q >> 3, e = q & 7;
        const int src = L*N_W2 + (nt*16 + (l&15))*HID + kt*32 + (l>>4)*8 + e;
        o2[i] = f2bf(W2[src]);
        o3[i] = f2bf(W3[src]);
    }
    for (int i = i0; i < NLAYERS*N_W4P; i += stride) {
        const int L = i >> 17, rem = i & (N_W4P - 1);
        const int c = rem >> 9, q = rem & 511;
        const int tb = c >> 5, pq = (c >> 2) & 7, kt = c & 3;
        const int l = q >> 3, e = q & 7;
        const int t = tb*4 + ((l & 15) >> 2);
        const int p = pq*4 + (l & 3);
        o4[i] = (p < PDIM)
              ? f2bf(W4[(size_t)L*N_W4 + (size_t)(t*PDIM + p)*HID + kt*32 + (l>>4)*8 + e])
              : (short)0;
    }
    for (int i = i0; i < NLAYERS*SPLIT*32; i += stride) {
        const int L = i >> 10, rem = i & 1023;
        const int t = rem >> 5, p = rem & 31;
        b4q[i] = (p < PDIM) ? b4[L*SPLIT*PDIM + t*PDIM + p] : 0.0f;
    }
}

// One coupling layer (R7 structure). W4+spline loop uses FULL-TILE prefetch:
// all 28 weight fragments of tile tb+1 are loaded into 28 distinct registers
// (112 VGPR, forced live across the spline) BEFORE spline(tb) runs, so the
// whole L2 latency drains under the spline chain; MFMAs consume afterwards.
// __launch_bounds__(NT,2): 256-VGPR budget (NT,4 spilled this in R14).
__global__ __launch_bounds__(NT, 2) void flow_layer(
    const float* xin, float* yout, float* logdet, const int first,
    const short* __restrict__ bW1, const float* __restrict__ b1,
    const short* __restrict__ bW2, const float* __restrict__ b2,
    const short* __restrict__ bW3, const float* __restrict__ b3,
    const short* __restrict__ bW4, const float* __restrict__ b4q,
    const int* __restrict__ mi, const int* __restrict__ ti)
{
    __shared__ short act[WAVES][32 * 64];         // 32 groups x 16 rows x 4 shorts
    __shared__ float xts[WAVES][ROWSW][33];       // spline inputs (f32)

    const int tid = threadIdx.x;
    const int wv  = tid >> 6;    // wave id
    const int l   = tid & 63;    // lane
    const int lr  = l & 15;      // row / col-in-tile
    const int lg  = l >> 4;      // 0..3
    const int rbase = blockIdx.x * MBLK + wv * ROWSW;

    short* const actw = &act[wv][0];

    // ---- gather: xm -> act groups 0..7 (bf16), xt -> xts (f32) ----
    {
        const int kcol = l & 31;
        const int mc = mi[kcol], tc = ti[kcol];
        const int r0 = l >> 5;                    // 0 or 1
        #pragma unroll
        for (int it = 0; it < 8; ++it) {
            const int r = r0 + it * 2;
            const float* row = xin + (size_t)(rbase + r) * DIM;
            const float mv = row[mc];
            actw[(kcol >> 2)*64 + r*4 + (kcol & 3)] = f2bf(mv);
            xts[wv][r][kcol] = row[tc];
            if (first) yout[(size_t)(rbase + r) * DIM + mc] = mv;  // copy-through (L0)
        }
    }

    // ================= h1 = relu(W1 @ xm^T + b1)  [K=32] =================
    {
        const bf16x8 afr0 = ldfrag(&actw[(2*lg)*64 + lr*4]);
        f32x4 c[8];
        #pragma unroll
        for (int nt = 0; nt < 8; ++nt) {
            const float4 bv = *reinterpret_cast<const float4*>(b1 + nt*16 + lg*4);
            c[nt] = (f32x4){bv.x, bv.y, bv.z, bv.w};
        }
        #pragma unroll
        for (int nt = 0; nt < 8; ++nt) {
            const bf16x8 wfr = *reinterpret_cast<const bf16x8*>(bW1 + (size_t)nt*512 + l*8);
            c[nt] = __builtin_amdgcn_mfma_f32_16x16x32_bf16(wfr, afr0, c[nt], 0, 0, 0);
        }
        #pragma unroll
        for (int nt = 0; nt < 8; ++nt) {
            const unsigned u0 = pk2(fmaxf(c[nt][0], 0.0f), fmaxf(c[nt][1], 0.0f));
            const unsigned u1 = pk2(fmaxf(c[nt][2], 0.0f), fmaxf(c[nt][3], 0.0f));
            *reinterpret_cast<uint2*>(&actw[(nt*4 + lg)*64 + lr*4]) = (uint2){u0, u1};
        }
    }

    // ================= h2 / h3  [K=128] =================
    #pragma unroll 1
    for (int ph = 0; ph < 2; ++ph) {
        const short* Wp = ph ? bW3 : bW2;
        const float* bp = ph ? b3  : b2;
        bf16x8 afr[4];
        #pragma unroll
        for (int kt = 0; kt < 4; ++kt)
            afr[kt] = ldfrag(&actw[(kt*8 + 2*lg)*64 + lr*4]);
        f32x4 c[8];
        #pragma unroll
        for (int nt = 0; nt < 8; ++nt) {
            const float4 bv = *reinterpret_cast<const float4*>(bp + nt*16 + lg*4);
            c[nt] = (f32x4){bv.x, bv.y, bv.z, bv.w};
        }
        #pragma unroll
        for (int kt = 0; kt < 4; ++kt)
            #pragma unroll
            for (int nt = 0; nt < 8; ++nt) {
                const bf16x8 wfr = *reinterpret_cast<const bf16x8*>(Wp + (size_t)(nt*4 + kt)*512 + l*8);
                c[nt] = __builtin_amdgcn_mfma_f32_16x16x32_bf16(wfr, afr[kt], c[nt], 0, 0, 0);
            }
        #pragma unroll
        for (int nt = 0; nt < 8; ++nt) {
            const unsigned u0 = pk2(fmaxf(c[nt][0], 0.0f), fmaxf(c[nt][1], 0.0f));
            const unsigned u1 = pk2(fmaxf(c[nt][2], 0.0f), fmaxf(c[nt][3], 0.0f));
            *reinterpret_cast<uint2*>(&actw[(nt*4 + lg)*64 + lr*4]) = (uint2){u0, u1};
        }
    }

    // ================= W4 params + RQS spline (full-tile prefetch) ==========
    bf16x8 afr[4];
    #pragma unroll
    for (int kt = 0; kt < 4; ++kt)
        afr[kt] = ldfrag(&actw[(kt*8 + 2*lg)*64 + lr*4]);

    float ldacc = 0.0f;
    f32x4 cA[7];
    bf16x8 wfr[28];                 // full tile in flight: 28 x 4 VGPR = 112

    // ---- prologue: tile 0 (loads stall here once; no spline to hide) ----
    {
        const int t0 = lg;
        #pragma unroll
        for (int pq = 0; pq < 7; ++pq) {
            const float4 bv = *reinterpret_cast<const float4*>(b4q + t0*32 + pq*4);
            cA[pq] = (f32x4){bv.x, bv.y, bv.z, bv.w};
        }
        #pragma unroll
        for (int kt = 0; kt < 4; ++kt)
            #pragma unroll
            for (int pq = 0; pq < 7; ++pq)
                wfr[kt*7 + pq] = *reinterpret_cast<const bf16x8*>(
                    bW4 + (size_t)((pq)*4 + kt)*512 + l*8);
        #pragma unroll
        for (int kt = 0; kt < 4; ++kt)
            #pragma unroll
            for (int pq = 0; pq < 7; ++pq)
                cA[pq] = __builtin_amdgcn_mfma_f32_16x16x32_bf16(wfr[kt*7 + pq], afr[kt], cA[pq], 0, 0, 0);
    }

    #pragma unroll 1
    for (int tb = 0; tb < 8; ++tb) {
        // ---- issue ALL 28 loads of tile tb+1 (fire-and-forget) ----
        if (tb < 7) {
            #pragma unroll
            for (int kt = 0; kt < 4; ++kt)
                #pragma unroll
                for (int pq = 0; pq < 7; ++pq)
                    wfr[kt*7 + pq] = *reinterpret_cast<const bf16x8*>(
                        bW4 + (size_t)(((tb+1)*8 + pq)*4 + kt)*512 + l*8);
        }

        // ---- spline(tb) on cA; covers the load latency ----
#define P(i) cA[(i)>>2][(i)&3]
        float wd[NBINS], hg[NBINS];
        #pragma unroll
        for (int i = 0; i < NBINS; ++i) wd[i] = __expf(P(i));
        #pragma unroll
        for (int i = 0; i < NBINS; ++i) hg[i] = __expf(P(NBINS + i));
        const float sw = ((wd[0]+wd[1]) + (wd[2]+wd[3])) + ((wd[4]+wd[5]) + (wd[6]+wd[7]));
        const float sh = ((hg[0]+hg[1]) + (hg[2]+hg[3])) + ((hg[4]+hg[5]) + (hg[6]+hg[7]));
        const float scw = __fdividef((R_MAX - R_MIN) - NBINS * MIN_BIN, sw);
        const float sch = __fdividef((R_MAX - R_MIN) - NBINS * MIN_BIN, sh);
        #pragma unroll
        for (int i = 0; i < NBINS; ++i) { wd[i] = wd[i]*scw + MIN_BIN; hg[i] = hg[i]*sch + MIN_BIN; }

        const float x = xts[wv][lr][tb*4 + lg];
        float cx = R_MIN, cy = R_MIN;
        float x_k = R_MIN, y_k = R_MIN, wsel = wd[0], hsel = hg[0];
        float z0 = P(16), z1 = P(17);
        #pragma unroll
        for (int i = 1; i < NBINS; ++i) {
            cx += wd[i-1]; cy += hg[i-1];
            const bool tk = (cx <= x);
            x_k  = tk ? cx : x_k;
            y_k  = tk ? cy : y_k;
            wsel = tk ? wd[i] : wsel;
            hsel = tk ? hg[i] : hsel;
            z0   = tk ? P(16 + i) : z0;
            z1   = tk ? P(17 + i) : z1;
        }

        auto sp = [](float v) {
            const float z = v + SOFF;
            return ((z > 15.0f) ? z : __logf(1.0f + __expf(z))) + MIN_SLOPE;
        };
        const float d_k = sp(z0), d_k1 = sp(z1);
        const float sl0 = sp(P(16)), sl8 = sp(P(24));
#undef P

        const float invw = __fdividef(1.0f, wsel);
        float xi = (x - x_k) * invw;
        xi = fminf(fmaxf(xi, 0.0f), 1.0f);
        const float s    = hsel * invw;
        const float xi1m = 1.0f - xi;
        const float q    = xi * xi1m;
        const float num  = s * xi * xi + d_k * q;
        const float den  = s + (d_k1 + d_k - 2.0f * s) * q;
        const float invden = __fdividef(1.0f, den);
        const float y_sp = y_k + hsel * num * invden;
        const float deriv = s * s * (d_k1 * xi * xi + 2.0f * s * q + d_k * xi1m * xi1m)
                            * invden * invden;

        const bool below = x < R_MIN;
        const bool above = x > R_MAX;
        const float yv = below ? ((x - R_MIN) * sl0 + R_MIN)
                       : (above ? ((x - R_MAX) * sl8 + R_MAX) : y_sp);
        const float dv = below ? sl0 : (above ? sl8 : deriv);
        ldacc += __logf(dv);
        yout[(size_t)(rbase + lr) * DIM + ti[tb*4 + lg]] = yv;

        // ---- consume wfr -> fresh cA (loads have drained under the spline) --
        if (tb < 7) {
            const int tn = (tb+1)*4 + lg;
            #pragma unroll
            for (int pq = 0; pq < 7; ++pq) {
                const float4 bv = *reinterpret_cast<const float4*>(b4q + tn*32 + pq*4);
                cA[pq] = (f32x4){bv.x, bv.y, bv.z, bv.w};
            }
            #pragma unroll
            for (int kt = 0; kt < 4; ++kt)
                #pragma unroll
                for (int pq = 0; pq < 7; ++pq)
                    cA[pq] = __builtin_amdgcn_mfma_f32_16x16x32_bf16(wfr[kt*7 + pq], afr[kt], cA[pq], 0, 0, 0);
        }
    }

    // per-row logdet: reduce over the 4 lane-groups (fixed order)
    ldacc += __shfl_xor(ldacc, 16, 64);
    ldacc += __shfl_xor(ldacc, 32, 64);
    if (l < 16) {
        const int row = rbase + lr;
        if (first) logdet[row] = ldacc;
        else       logdet[row] += ldacc;
    }
}

extern "C" void kernel_launch(void* const* d_in, const int* in_sizes, int n_in,
                              void* d_out, int out_size, void* d_ws, size_t ws_size,
                              hipStream_t stream) {
    const float* x  = (const float*)d_in[0];
    const float* W1 = (const float*)d_in[1];
    const float* b1 = (const float*)d_in[2];
    const float* W2 = (const float*)d_in[3];
    const float* b2 = (const float*)d_in[4];
    const float* W3 = (const float*)d_in[5];
    const float* b3 = (const float*)d_in[6];
    const float* W4 = (const float*)d_in[7];
    const float* b4 = (const float*)d_in[8];
    const int*   mi = (const int*)d_in[9];
    const int*   ti = (const int*)d_in[10];

    float* y      = (float*)d_out;
    float* logdet = y + (size_t)BATCH * DIM;

    short* bW1 = (short*)d_ws;
    short* bW2 = bW1 + NLAYERS * N_W1;
    short* bW3 = bW2 + NLAYERS * N_W2;
    short* bW4 = bW3 + NLAYERS * N_W2;
    float* b4q = (float*)(bW4 + (size_t)NLAYERS * N_W4P);

    cvt_weights<<<512, 256, 0, stream>>>(W1, W2, W3, W4, b4, bW1, bW2, bW3, bW4, b4q);

    dim3 grid(BATCH / MBLK), block(NT);
    for (int L = 0; L < NLAYERS; ++L) {
        flow_layer<<<grid, block, 0, stream>>>(
            (L == 0) ? x : y, y, logdet, (L == 0) ? 1 : 0,
            bW1 + (size_t)L * N_W1, b1 + L * HID,
            bW2 + (size_t)L * N_W2, b2 + L * HID,
            bW3 + (size_t)L * N_W2, b3 + L * HID,
            bW4 + (size_t)L * N_W4P, b4q + (size_t)L * SPLIT * 32,
            mi + L * SPLIT, ti + L * SPLIT);
    }
}

// Round 17
// 395.914 us; speedup vs baseline: 1.0174x; 1.0174x over previous
//
#include <hip/hip_runtime.h>
#include <math.h>

#define BATCH   65536
#define DIM     64
#define HID     128
#define SPLIT   32
#define NBINS   8
#define PDIM    25          // 3*NBINS+1
#define NLAYERS 6
#define R_MIN   (-5.0f)
#define R_MAX   (5.0f)
#define MIN_BIN   1.0e-4f
#define MIN_SLOPE 1.0e-4f
#define SOFF      0.54116666f   // log(exp(1-MIN_SLOPE)-1)

#define ROWSW 16      // rows per wave
#define WAVES 4
#define MBLK  64      // rows per block
#define NT    256

#define N_W1  (HID*SPLIT)      // 4096
#define N_W2  (HID*HID)        // 16384
#define N_W4P (32*32*HID)      // 131072 (8 tb x 8 pq x 4 kt chunks of 512)
#define N_W4  (SPLIT*PDIM*HID) // 102400

typedef __attribute__((ext_vector_type(8))) short bf16x8;
typedef __attribute__((ext_vector_type(4))) float f32x4;

__device__ __forceinline__ short f2bf(float f) {
    unsigned u = __builtin_bit_cast(unsigned, f);
    unsigned r = u + 0x7FFFu + ((u >> 16) & 1u);   // RNE
    return (short)(r >> 16);
}

__device__ __forceinline__ unsigned pk2(float a, float b) {   // 2xf32 -> packed bf16 (RNE)
    unsigned r;
    asm("v_cvt_pk_bf16_f32 %0, %1, %2" : "=v"(r) : "v"(a), "v"(b));
    return r;
}

// act LDS layout: [group g = k>>2][row r][k&3] shorts, group stride 64 shorts.
__device__ __forceinline__ bf16x8 ldfrag(const short* base) {
    short4 lo = *reinterpret_cast<const short4*>(base);
    short4 hi = *reinterpret_cast<const short4*>(base + 64);
    bf16x8 a;
    a[0]=lo.x; a[1]=lo.y; a[2]=lo.z; a[3]=lo.w;
    a[4]=hi.x; a[5]=hi.y; a[6]=hi.z; a[7]=hi.w;
    return a;
}

// ---- weight conversion prologue (fragment packing, same as R5-R16) ----
__global__ void cvt_weights(const float* __restrict__ W1, const float* __restrict__ W2,
                            const float* __restrict__ W3, const float* __restrict__ W4,
                            const float* __restrict__ b4,
                            short* __restrict__ o1, short* __restrict__ o2,
                            short* __restrict__ o3, short* __restrict__ o4,
                            float* __restrict__ b4q) {
    const int stride = gridDim.x * blockDim.x;
    const int i0 = blockIdx.x * blockDim.x + threadIdx.x;
    for (int i = i0; i < NLAYERS*N_W1; i += stride) {
        const int L = i >> 12, rem = i & 4095;
        const int nt = rem >> 9, q = rem & 511;
        const int l = q >> 3, e = q & 7;
        o1[i] = f2bf(W1[L*N_W1 + (nt*16 + (l&15))*SPLIT + (l>>4)*8 + e]);
    }
    for (int i = i0; i < NLAYERS*N_W2; i += stride) {
        const int L = i >> 14, rem = i & 16383;
        const int c = rem >> 9, q = rem & 511;
        const int nt = c >> 2, kt = c & 3;
        const int l = q >> 3, e = q & 7;
        const int src = L*N_W2 + (nt*16 + (l&15))*HID + kt*32 + (l>>4)*8 + e;
        o2[i] = f2bf(W2[src]);
        o3[i] = f2bf(W3[src]);
    }
    for (int i = i0; i < NLAYERS*N_W4P; i += stride) {
        const int L = i >> 17, rem = i & (N_W4P - 1);
        const int c = rem >> 9, q = rem & 511;
        const int tb = c >> 5, pq = (c >> 2) & 7, kt = c & 3;
        const int l = q >> 3, e = q & 7;
        const int t = tb*4 + ((l & 15) >> 2);
        const int p = pq*4 + (l & 3);
        o4[i] = (p < PDIM)
              ? f2bf(W4[(size_t)L*N_W4 + (size_t)(t*PDIM + p)*HID + kt*32 + (l>>4)*8 + e])
              : (short)0;
    }
    for (int i = i0; i < NLAYERS*SPLIT*32; i += stride) {
        const int L = i >> 10, rem = i & 1023;
        const int t = rem >> 5, p = rem & 31;
        b4q[i] = (p < PDIM) ? b4[L*SPLIT*PDIM + t*PDIM + p] : 0.0f;
    }
}

// One coupling layer (R7 structure). W4+spline loop: full-tile prefetch of
// tile tb+1 (28 fragments + bias) issued BEFORE spline(tb), PINNED by
// sched_barrier(0) so the LLVM scheduler cannot sink the loads to their
// uses (it did in R16: VGPR=100, loads serialized). Fragments stay live
// across the spline -> L2 latency drains under ~600cyc of spline VALU.
__global__ __launch_bounds__(NT, 2) void flow_layer(
    const float* xin, float* yout, float* logdet, const int first,
    const short* __restrict__ bW1, const float* __restrict__ b1,
    const short* __restrict__ bW2, const float* __restrict__ b2,
    const short* __restrict__ bW3, const float* __restrict__ b3,
    const short* __restrict__ bW4, const float* __restrict__ b4q,
    const int* __restrict__ mi, const int* __restrict__ ti)
{
    __shared__ short act[WAVES][32 * 64];         // 32 groups x 16 rows x 4 shorts
    __shared__ float xts[WAVES][ROWSW][33];       // spline inputs (f32)

    const int tid = threadIdx.x;
    const int wv  = tid >> 6;    // wave id
    const int l   = tid & 63;    // lane
    const int lr  = l & 15;      // row / col-in-tile
    const int lg  = l >> 4;      // 0..3
    const int rbase = blockIdx.x * MBLK + wv * ROWSW;

    short* const actw = &act[wv][0];

    // ---- gather: xm -> act groups 0..7 (bf16), xt -> xts (f32) ----
    {
        const int kcol = l & 31;
        const int mc = mi[kcol], tc = ti[kcol];
        const int r0 = l >> 5;                    // 0 or 1
        #pragma unroll
        for (int it = 0; it < 8; ++it) {
            const int r = r0 + it * 2;
            const float* row = xin + (size_t)(rbase + r) * DIM;
            const float mv = row[mc];
            actw[(kcol >> 2)*64 + r*4 + (kcol & 3)] = f2bf(mv);
            xts[wv][r][kcol] = row[tc];
            if (first) yout[(size_t)(rbase + r) * DIM + mc] = mv;  // copy-through (L0)
        }
    }

    // ================= h1 = relu(W1 @ xm^T + b1)  [K=32] =================
    {
        const bf16x8 afr0 = ldfrag(&actw[(2*lg)*64 + lr*4]);
        f32x4 c[8];
        #pragma unroll
        for (int nt = 0; nt < 8; ++nt) {
            const float4 bv = *reinterpret_cast<const float4*>(b1 + nt*16 + lg*4);
            c[nt] = (f32x4){bv.x, bv.y, bv.z, bv.w};
        }
        #pragma unroll
        for (int nt = 0; nt < 8; ++nt) {
            const bf16x8 wfr = *reinterpret_cast<const bf16x8*>(bW1 + (size_t)nt*512 + l*8);
            c[nt] = __builtin_amdgcn_mfma_f32_16x16x32_bf16(wfr, afr0, c[nt], 0, 0, 0);
        }
        #pragma unroll
        for (int nt = 0; nt < 8; ++nt) {
            const unsigned u0 = pk2(fmaxf(c[nt][0], 0.0f), fmaxf(c[nt][1], 0.0f));
            const unsigned u1 = pk2(fmaxf(c[nt][2], 0.0f), fmaxf(c[nt][3], 0.0f));
            *reinterpret_cast<uint2*>(&actw[(nt*4 + lg)*64 + lr*4]) = (uint2){u0, u1};
        }
    }

    // ================= h2 / h3  [K=128] =================
    #pragma unroll 1
    for (int ph = 0; ph < 2; ++ph) {
        const short* Wp = ph ? bW3 : bW2;
        const float* bp = ph ? b3  : b2;
        bf16x8 afr[4];
        #pragma unroll
        for (int kt = 0; kt < 4; ++kt)
            afr[kt] = ldfrag(&actw[(kt*8 + 2*lg)*64 + lr*4]);
        f32x4 c[8];
        #pragma unroll
        for (int nt = 0; nt < 8; ++nt) {
            const float4 bv = *reinterpret_cast<const float4*>(bp + nt*16 + lg*4);
            c[nt] = (f32x4){bv.x, bv.y, bv.z, bv.w};
        }
        #pragma unroll
        for (int kt = 0; kt < 4; ++kt)
            #pragma unroll
            for (int nt = 0; nt < 8; ++nt) {
                const bf16x8 wfr = *reinterpret_cast<const bf16x8*>(Wp + (size_t)(nt*4 + kt)*512 + l*8);
                c[nt] = __builtin_amdgcn_mfma_f32_16x16x32_bf16(wfr, afr[kt], c[nt], 0, 0, 0);
            }
        #pragma unroll
        for (int nt = 0; nt < 8; ++nt) {
            const unsigned u0 = pk2(fmaxf(c[nt][0], 0.0f), fmaxf(c[nt][1], 0.0f));
            const unsigned u1 = pk2(fmaxf(c[nt][2], 0.0f), fmaxf(c[nt][3], 0.0f));
            *reinterpret_cast<uint2*>(&actw[(nt*4 + lg)*64 + lr*4]) = (uint2){u0, u1};
        }
    }

    // ================= W4 params + RQS spline (pinned prefetch) =============
    bf16x8 afr[4];
    #pragma unroll
    for (int kt = 0; kt < 4; ++kt)
        afr[kt] = ldfrag(&actw[(kt*8 + 2*lg)*64 + lr*4]);

    float ldacc = 0.0f;
    f32x4 cA[7];
    bf16x8 wfr[28];                 // full tile in flight: 28 x 4 VGPR = 112
    float4 bnx[7];                  // prefetched bias of tile tb+1

    // ---- prologue: tile 0 (loads stall here once; no spline to hide) ----
    {
        const int t0 = lg;
        #pragma unroll
        for (int pq = 0; pq < 7; ++pq) {
            const float4 bv = *reinterpret_cast<const float4*>(b4q + t0*32 + pq*4);
            cA[pq] = (f32x4){bv.x, bv.y, bv.z, bv.w};
        }
        #pragma unroll
        for (int kt = 0; kt < 4; ++kt)
            #pragma unroll
            for (int pq = 0; pq < 7; ++pq)
                wfr[kt*7 + pq] = *reinterpret_cast<const bf16x8*>(
                    bW4 + (size_t)((pq)*4 + kt)*512 + l*8);
        #pragma unroll
        for (int kt = 0; kt < 4; ++kt)
            #pragma unroll
            for (int pq = 0; pq < 7; ++pq)
                cA[pq] = __builtin_amdgcn_mfma_f32_16x16x32_bf16(wfr[kt*7 + pq], afr[kt], cA[pq], 0, 0, 0);
    }

    #pragma unroll 1
    for (int tb = 0; tb < 8; ++tb) {
        // ---- issue ALL 28 weight loads + 7 bias loads of tile tb+1 ----
        if (tb < 7) {
            #pragma unroll
            for (int kt = 0; kt < 4; ++kt)
                #pragma unroll
                for (int pq = 0; pq < 7; ++pq)
                    wfr[kt*7 + pq] = *reinterpret_cast<const bf16x8*>(
                        bW4 + (size_t)(((tb+1)*8 + pq)*4 + kt)*512 + l*8);
            const int tn = (tb+1)*4 + lg;
            #pragma unroll
            for (int pq = 0; pq < 7; ++pq)
                bnx[pq] = *reinterpret_cast<const float4*>(b4q + tn*32 + pq*4);
        }
        // PIN: nothing may cross -- loads stay issued HERE, before the spline.
        __builtin_amdgcn_sched_barrier(0);

        // ---- spline(tb) on cA; covers the load latency ----
#define P(i) cA[(i)>>2][(i)&3]
        float wd[NBINS], hg[NBINS];
        #pragma unroll
        for (int i = 0; i < NBINS; ++i) wd[i] = __expf(P(i));
        #pragma unroll
        for (int i = 0; i < NBINS; ++i) hg[i] = __expf(P(NBINS + i));
        const float sw = ((wd[0]+wd[1]) + (wd[2]+wd[3])) + ((wd[4]+wd[5]) + (wd[6]+wd[7]));
        const float sh = ((hg[0]+hg[1]) + (hg[2]+hg[3])) + ((hg[4]+hg[5]) + (hg[6]+hg[7]));
        const float scw = __fdividef((R_MAX - R_MIN) - NBINS * MIN_BIN, sw);
        const float sch = __fdividef((R_MAX - R_MIN) - NBINS * MIN_BIN, sh);
        #pragma unroll
        for (int i = 0; i < NBINS; ++i) { wd[i] = wd[i]*scw + MIN_BIN; hg[i] = hg[i]*sch + MIN_BIN; }

        const float x = xts[wv][lr][tb*4 + lg];
        float cx = R_MIN, cy = R_MIN;
        float x_k = R_MIN, y_k = R_MIN, wsel = wd[0], hsel = hg[0];
        float z0 = P(16), z1 = P(17);
        #pragma unroll
        for (int i = 1; i < NBINS; ++i) {
            cx += wd[i-1]; cy += hg[i-1];
            const bool tk = (cx <= x);
            x_k  = tk ? cx : x_k;
            y_k  = tk ? cy : y_k;
            wsel = tk ? wd[i] : wsel;
            hsel = tk ? hg[i] : hsel;
            z0   = tk ? P(16 + i) : z0;
            z1   = tk ? P(17 + i) : z1;
        }

        auto sp = [](float v) {
            const float z = v + SOFF;
            return ((z > 15.0f) ? z : __logf(1.0f + __expf(z))) + MIN_SLOPE;
        };
        const float d_k = sp(z0), d_k1 = sp(z1);
        const float sl0 = sp(P(16)), sl8 = sp(P(24));
#undef P

        const float invw = __fdividef(1.0f, wsel);
        float xi = (x - x_k) * invw;
        xi = fminf(fmaxf(xi, 0.0f), 1.0f);
        const float s    = hsel * invw;
        const float xi1m = 1.0f - xi;
        const float q    = xi * xi1m;
        const float num  = s * xi * xi + d_k * q;
        const float den  = s + (d_k1 + d_k - 2.0f * s) * q;
        const float invden = __fdividef(1.0f, den);
        const float y_sp = y_k + hsel * num * invden;
        const float deriv = s * s * (d_k1 * xi * xi + 2.0f * s * q + d_k * xi1m * xi1m)
                            * invden * invden;

        const bool below = x < R_MIN;
        const bool above = x > R_MAX;
        const float yv = below ? ((x - R_MIN) * sl0 + R_MIN)
                       : (above ? ((x - R_MAX) * sl8 + R_MAX) : y_sp);
        const float dv = below ? sl0 : (above ? sl8 : deriv);
        ldacc += __logf(dv);
        yout[(size_t)(rbase + lr) * DIM + ti[tb*4 + lg]] = yv;

        // ---- consume wfr -> fresh cA (loads drained under the spline) ----
        if (tb < 7) {
            #pragma unroll
            for (int pq = 0; pq < 7; ++pq)
                cA[pq] = (f32x4){bnx[pq].x, bnx[pq].y, bnx[pq].z, bnx[pq].w};
            #pragma unroll
            for (int kt = 0; kt < 4; ++kt)
                #pragma unroll
                for (int pq = 0; pq < 7; ++pq)
                    cA[pq] = __builtin_amdgcn_mfma_f32_16x16x32_bf16(wfr[kt*7 + pq], afr[kt], cA[pq], 0, 0, 0);
        }
    }

    // per-row logdet: reduce over the 4 lane-groups (fixed order)
    ldacc += __shfl_xor(ldacc, 16, 64);
    ldacc += __shfl_xor(ldacc, 32, 64);
    if (l < 16) {
        const int row = rbase + lr;
        if (first) logdet[row] = ldacc;
        else       logdet[row] += ldacc;
    }
}

extern "C" void kernel_launch(void* const* d_in, const int* in_sizes, int n_in,
                              void* d_out, int out_size, void* d_ws, size_t ws_size,
                              hipStream_t stream) {
    const float* x  = (const float*)d_in[0];
    const float* W1 = (const float*)d_in[1];
    const float* b1 = (const float*)d_in[2];
    const float* W2 = (const float*)d_in[3];
    const float* b2 = (const float*)d_in[4];
    const float* W3 = (const float*)d_in[5];
    const float* b3 = (const float*)d_in[6];
    const float* W4 = (const float*)d_in[7];
    const float* b4 = (const float*)d_in[8];
    const int*   mi = (const int*)d_in[9];
    const int*   ti = (const int*)d_in[10];

    float* y      = (float*)d_out;
    float* logdet = y + (size_t)BATCH * DIM;

    short* bW1 = (short*)d_ws;
    short* bW2 = bW1 + NLAYERS * N_W1;
    short* bW3 = bW2 + NLAYERS * N_W2;
    short* bW4 = bW3 + NLAYERS * N_W2;
    float* b4q = (float*)(bW4 + (size_t)NLAYERS * N_W4P);

    cvt_weights<<<512, 256, 0, stream>>>(W1, W2, W3, W4, b4, bW1, bW2, bW3, bW4, b4q);

    dim3 grid(BATCH / MBLK), block(NT);
    for (int L = 0; L < NLAYERS; ++L) {
        flow_layer<<<grid, block, 0, stream>>>(
            (L == 0) ? x : y, y, logdet, (L == 0) ? 1 : 0,
            bW1 + (size_t)L * N_W1, b1 + L * HID,
            bW2 + (size_t)L * N_W2, b2 + L * HID,
            bW3 + (size_t)L * N_W2, b3 + L * HID,
            bW4 + (size_t)L * N_W4P, b4q + (size_t)L * SPLIT * 32,
            mi + L * SPLIT, ti + L * SPLIT);
    }
}